// Round 8
// baseline (531.502 us; speedup 1.0000x reference)
//
#include <hip/hip_runtime.h>
#include <hip/hip_bf16.h>

// BaseEntropyCoder: 4-layer residual MLP with parent-gather, bf16 MFMA pipeline.
// B=8, N=65536, D=128, OUT=256, M=524288 rows.
//
// R8 = R7 base with rb retiled to 32-row tiles:
//  - LDS 40KB (At 2x16KB dbuf + Hl 8KB), __launch_bounds__(256,3) -> 3 blocks/CU
//    (12 waves vs 8): more independent pipelines to hide body latency.
//  - grid 1024 blocks x 16 tiles; entry BAR_VM(8) (4 stage + 4 par newest).
// stage1 / fc / prep / pidx unchanged.
// R5 lesson: no loop-carried global loads consumed mid-loop (vmcnt FIFO).
// R6 lesson: keep LDS repack + coalesced copy-out; keep fc LDS-staged.

typedef __bf16 bf16;
typedef bf16 bf16x8 __attribute__((ext_vector_type(8)));
typedef bf16 bf16x4 __attribute__((ext_vector_type(4)));
typedef float f32x4 __attribute__((ext_vector_type(4)));

#define MFMA16(a, b, c) __builtin_amdgcn_mfma_f32_16x16x32_bf16((a), (b), (c), 0, 0, 0)

#define BAR_LGKM() asm volatile("s_waitcnt lgkmcnt(0)\ns_barrier" ::: "memory")
#define BAR_VM(N) asm volatile("s_waitcnt vmcnt(" #N ")\ns_barrier" ::: "memory")

// ---- ws layout ----
#define ZB    0
#define W10T  128
#define W11T  4224
#define W20T  20608
#define W21T  53376
#define W30T  69760
#define W31T  102528
#define W40T  118912
#define W41T  151680
#define WFCT  168064
#define PREP_TOTAL 200832
#define FA_BYTE  524288
#define F_STRIDE 134221824   // 524289 rows * 256B, padded
#define FB_BYTE  (FA_BYTE + F_STRIDE)
#define PT_BYTE  (FA_BYTE + 2 * F_STRIDE)
#define ZROW_IDX 524288

__device__ __forceinline__ void gload16(const void* g, void* l) {
  __builtin_amdgcn_global_load_lds(
      (__attribute__((address_space(1))) void*)(g),
      (__attribute__((address_space(3))) void*)(l), 16, 0, 0);
}

// ---------------- weight prep: fp32 -> bf16, transposed ----------------
__global__ void prep_kernel(const float* __restrict__ W1_0, const float* __restrict__ W1_1,
                            const float* __restrict__ W2_0, const float* __restrict__ W2_1,
                            const float* __restrict__ W3_0, const float* __restrict__ W3_1,
                            const float* __restrict__ W4_0, const float* __restrict__ W4_1,
                            const float* __restrict__ Wfc, bf16* __restrict__ wsb) {
  int i = blockIdx.x * 256 + threadIdx.x;
  if (i < 128) { wsb[ZB + i] = (bf16)0.0f; return; }
  i -= 128;
  if (i < 4096) { int n = i >> 5, k = i & 31;
    wsb[W10T + i] = (bf16)((k < 6) ? W1_0[k * 128 + n] : 0.0f); return; }
  i -= 4096;
  if (i < 16384) { int n = i >> 7, k = i & 127; wsb[W11T + i] = (bf16)W1_1[k * 128 + n]; return; }
  i -= 16384;
  if (i < 32768) { int n = i >> 8, k = i & 255; wsb[W20T + i] = (bf16)W2_0[k * 128 + n]; return; }
  i -= 32768;
  if (i < 16384) { int n = i >> 7, k = i & 127; wsb[W21T + i] = (bf16)W2_1[k * 128 + n]; return; }
  i -= 16384;
  if (i < 32768) { int n = i >> 8, k = i & 255; wsb[W30T + i] = (bf16)W3_0[k * 128 + n]; return; }
  i -= 32768;
  if (i < 16384) { int n = i >> 7, k = i & 127; wsb[W31T + i] = (bf16)W3_1[k * 128 + n]; return; }
  i -= 16384;
  if (i < 32768) { int n = i >> 8, k = i & 255; wsb[W40T + i] = (bf16)W4_0[k * 128 + n]; return; }
  i -= 32768;
  if (i < 16384) { int n = i >> 7, k = i & 127; wsb[W41T + i] = (bf16)W4_1[k * 128 + n]; return; }
  i -= 16384;
  if (i < 32768) { int n = i >> 7, k = i & 127; wsb[WFCT + i] = (bf16)Wfc[k * 256 + n]; return; }
}

// ---------------- parent index table + zero-row init ----------------
__global__ void pidx_kernel(const float* __restrict__ data, int* __restrict__ partab,
                            bf16* __restrict__ fA, bf16* __restrict__ fB) {
  int m = blockIdx.x * 256 + threadIdx.x;
  float2 pr = *(const float2*)(data + (long)m * 8 + 6);
  partab[m] = (pr.y == 1.0f) ? ZROW_IDX : ((m & ~65535) + (int)pr.x);
  if (m < 128) {
    fA[(long)ZROW_IDX * 128 + m] = (bf16)0.0f;
    fB[(long)ZROW_IDX * 128 + m] = (bf16)0.0f;
  }
}

// ---- stage one 32-row concat(f,parent) tile: 4 gload16 per thread ----
__device__ __forceinline__ void stage_tile32(const bf16* __restrict__ f_in, const int* par,
                                             long mt0, char* dst, int tid) {
  const int wv = tid >> 6;
#pragma unroll
  for (int r = 0; r < 4; ++r) {
    int row = r * 8 + (tid >> 5);
    int gp = tid & 31;
    int g = (gp & 8) | ((gp & 7) ^ (row & 7));
    const bf16* base = (gp < 16) ? (f_in + (mt0 + row) * 128) : (f_in + (long)par[r] * 128);
    gload16(base + g * 8, dst + (r * 256 + wv * 64) * 16);
  }
}

// ---- stage one 64-row f tile (fc): 4 VMEM ops ----
__device__ __forceinline__ void stage_ftile(const bf16* __restrict__ f_in, long mt0,
                                            char* dst, int tid) {
  const int wv = tid >> 6;
#pragma unroll
  for (int r = 0; r < 4; ++r) {
    int G = r * 256 + tid, row = G >> 4, gl = G & 15;
    int g = (gl & 8) | ((gl & 7) ^ (row & 7));
    gload16(f_in + (mt0 + row) * 128 + g * 8, dst + (r * 256 + wv * 64) * 16);
  }
}

// ---------------- stage 1: f1 = relu(x@W1_0+b)@W1_1+b, pipelined x8 tiles ----
__global__ __launch_bounds__(256, 3) void stage1_kernel(
    const float* __restrict__ data, const bf16* __restrict__ w0t, const float* __restrict__ b0,
    const bf16* __restrict__ w1t, const float* __restrict__ b1, bf16* __restrict__ f_out) {
  __shared__ alignas(128) char Hb[2][16384];  // [64][256B] bf16, swizzled, dbuf

  const int tid = threadIdx.x;
  const int lane = tid & 63, wv = tid >> 6;
  const int lr = lane & 15, lq = lane >> 4;
  const long brow = (long)blockIdx.x * 512;
  const int n0 = wv * 32;

  bf16x8 w0f[2];
#pragma unroll
  for (int nf = 0; nf < 2; ++nf)
    w0f[nf] = *(const bf16x8*)(w0t + (long)(n0 + nf * 16 + lr) * 32 + lq * 8);
  bf16x8 w1f[4][2];
#pragma unroll
  for (int kc = 0; kc < 4; ++kc)
#pragma unroll
    for (int nf = 0; nf < 2; ++nf)
      w1f[kc][nf] = *(const bf16x8*)(w1t + (long)(n0 + nf * 16 + lr) * 128 + kc * 32 + lq * 8);
  f32x4 b0v[2], b1v[2];
#pragma unroll
  for (int nf = 0; nf < 2; ++nf) {
    b0v[nf] = *(const f32x4*)(b0 + n0 + nf * 16 + lq * 4);
    b1v[nf] = *(const f32x4*)(b1 + n0 + nf * 16 + lq * 4);
  }

  float4 xlo[4], xhi[4];
  if (lq == 0) {
#pragma unroll
    for (int mf = 0; mf < 4; ++mf) {
      const float* dp = data + (brow + mf * 16 + lr) * 8;
      xlo[mf] = *(const float4*)dp;
      xhi[mf] = *(const float4*)(dp + 4);
    }
  }

#pragma unroll 1
  for (int t = 0; t < 8; ++t) {
    bf16x8 xa[4];
#pragma unroll
    for (int mf = 0; mf < 4; ++mf) {
#pragma unroll
      for (int j = 0; j < 8; ++j) xa[mf][j] = (bf16)0.0f;
      if (lq == 0) {
#pragma unroll
        for (int j = 0; j < 4; ++j) xa[mf][j] = (bf16)xlo[mf][j];
        xa[mf][4] = (bf16)xhi[mf][0];
        xa[mf][5] = (bf16)xhi[mf][1];
      }
    }
    if (lq == 0) {  // prefetch next tile's rows
      long nb = brow + (long)((t < 7) ? t + 1 : 7) * 64;
#pragma unroll
      for (int mf = 0; mf < 4; ++mf) {
        const float* dp = data + (nb + mf * 16 + lr) * 8;
        xlo[mf] = *(const float4*)dp;
        xhi[mf] = *(const float4*)(dp + 4);
      }
    }

    // GEMM1 (K=32, 6 real)
    f32x4 acc[4][2];
#pragma unroll
    for (int mf = 0; mf < 4; ++mf)
#pragma unroll
      for (int nf = 0; nf < 2; ++nf) acc[mf][nf] = b0v[nf];
#pragma unroll
    for (int mf = 0; mf < 4; ++mf)
#pragma unroll
      for (int nf = 0; nf < 2; ++nf) acc[mf][nf] = MFMA16(w0f[nf], xa[mf], acc[mf][nf]);

    char* H = Hb[t & 1];
    // relu -> H
#pragma unroll
    for (int mf = 0; mf < 4; ++mf)
#pragma unroll
      for (int nf = 0; nf < 2; ++nf) {
        int row = mf * 16 + lr, nc = n0 + nf * 16 + lq * 4;
        bf16x4 p;
#pragma unroll
        for (int j = 0; j < 4; ++j) p[j] = (bf16)fmaxf(acc[mf][nf][j], 0.0f);
        int g = nc >> 3, gp = (g & 8) | ((g & 7) ^ (row & 7));
        *(bf16x4*)(H + row * 256 + gp * 16 + (nc & 7) * 2) = p;
      }
    BAR_LGKM();  // H published

    // GEMM2 (K=128)
    f32x4 acc2[4][2];
#pragma unroll
    for (int mf = 0; mf < 4; ++mf)
#pragma unroll
      for (int nf = 0; nf < 2; ++nf) acc2[mf][nf] = b1v[nf];
#pragma unroll
    for (int kc = 0; kc < 4; ++kc) {
      bf16x8 a[4];
#pragma unroll
      for (int mf = 0; mf < 4; ++mf) {
        int row = mf * 16 + lr, g = kc * 4 + lq;
        int gp = (g & 8) | ((g & 7) ^ (row & 7));
        a[mf] = *(const bf16x8*)(H + row * 256 + gp * 16);
      }
#pragma unroll
      for (int mf = 0; mf < 4; ++mf)
#pragma unroll
        for (int nf = 0; nf < 2; ++nf) acc2[mf][nf] = MFMA16(w1f[kc][nf], a[mf], acc2[mf][nf]);
    }
    BAR_LGKM();  // all H reads done

    // repack -> H
#pragma unroll
    for (int mf = 0; mf < 4; ++mf)
#pragma unroll
      for (int nf = 0; nf < 2; ++nf) {
        int row = mf * 16 + lr, nc = n0 + nf * 16 + lq * 4;
        bf16x4 p;
#pragma unroll
        for (int j = 0; j < 4; ++j) p[j] = (bf16)acc2[mf][nf][j];
        int g = nc >> 3, gp = (g & 8) | ((g & 7) ^ (row & 7));
        *(bf16x4*)(H + row * 256 + gp * 16 + (nc & 7) * 2) = p;
      }
    BAR_LGKM();  // f1 tile complete

    // coalesced copy-out
    long mt0 = brow + (long)t * 64;
#pragma unroll
    for (int r = 0; r < 4; ++r) {
      int G = r * 256 + tid, row = G >> 4, gl = G & 15;
      int gp = (gl & 8) | ((gl & 7) ^ (row & 7));
      bf16x8 v = *(const bf16x8*)(H + row * 256 + gp * 16);
      *(bf16x8*)(f_out + (mt0 + row) * 128 + gl * 8) = v;
    }
  }
}

// ---------------- residual block, 32-row tiles x16, 3 blocks/CU ----------------
__global__ __launch_bounds__(256, 3) void resblock_kernel(
    const bf16* __restrict__ f_in, const bf16* __restrict__ w0t, const float* __restrict__ b0,
    const bf16* __restrict__ w1t, const float* __restrict__ b1,
    const int* __restrict__ partab, bf16* __restrict__ f_out) {
  // At: [32 rows][512B] concat(f, parent), swizzled, dbuf. Hl: [32][256B].
  __shared__ alignas(128) char At[2][16384];
  __shared__ alignas(128) char Hl[8192];

  const int tid = threadIdx.x;
  const int lane = tid & 63, wv = tid >> 6;
  const int lr = lane & 15, lq = lane >> 4;
  const int prow = tid >> 5;
  const long brow = (long)blockIdx.x * 512;
  const int n0 = wv * 32;

  // resident weights + biases
  bf16x8 w0f[8][2];
#pragma unroll
  for (int kc = 0; kc < 8; ++kc)
#pragma unroll
    for (int nf = 0; nf < 2; ++nf)
      w0f[kc][nf] = *(const bf16x8*)(w0t + (long)(n0 + nf * 16 + lr) * 256 + kc * 32 + lq * 8);
  bf16x8 w1f[4][2];
#pragma unroll
  for (int kc = 0; kc < 4; ++kc)
#pragma unroll
    for (int nf = 0; nf < 2; ++nf)
      w1f[kc][nf] = *(const bf16x8*)(w1t + (long)(n0 + nf * 16 + lr) * 128 + kc * 32 + lq * 8);
  f32x4 b0v[2], b1v[2];
#pragma unroll
  for (int nf = 0; nf < 2; ++nf) {
    b0v[nf] = *(const f32x4*)(b0 + n0 + nf * 16 + lq * 4);
    b1v[nf] = *(const f32x4*)(b1 + n0 + nf * 16 + lq * 4);
  }

  // parent-index register pipeline: par_s feeds the NEXT stage call
  int par_s[4], par_n[4];
  {
    int p0[4];
#pragma unroll
    for (int r = 0; r < 4; ++r) p0[r] = partab[brow + r * 8 + prow];
    stage_tile32(f_in, p0, brow, At[0], tid);  // stage(0): 4 gload16
  }
#pragma unroll
  for (int r = 0; r < 4; ++r) par_s[r] = partab[brow + 32 + r * 8 + prow];

#pragma unroll 1
  for (int t = 0; t < 16; ++t) {
    // stage(t+1) (dummy re-stage of tile 15 at t=15); par_s loaded last iter
    stage_tile32(f_in, par_s, brow + (long)((t < 15) ? t + 1 : 15) * 32, At[(t + 1) & 1], tid);
    // parents for the stage call of iter t+1 (tile min(t+2,15))
    {
      long pb = brow + (long)((t < 14) ? t + 2 : 15) * 32;
#pragma unroll
      for (int r = 0; r < 4; ++r) par_n[r] = partab[pb + r * 8 + prow];
    }
    // entry: everything except the 8 newest (stage(t+1)+par_n) retired
    BAR_VM(8);
    char* A = At[t & 1];

    // ---- GEMM1: h = relu([f|par] @ W0 + b0) ----
    f32x4 acc[2][2];
#pragma unroll
    for (int mf = 0; mf < 2; ++mf)
#pragma unroll
      for (int nf = 0; nf < 2; ++nf) acc[mf][nf] = b0v[nf];
#pragma unroll
    for (int kc = 0; kc < 8; ++kc) {
      bf16x8 a[2];
#pragma unroll
      for (int mf = 0; mf < 2; ++mf) {
        int row = mf * 16 + lr, g = kc * 4 + lq;
        int gp = (g & 24) | ((g & 7) ^ (row & 7));
        a[mf] = *(const bf16x8*)(A + row * 512 + gp * 16);
      }
#pragma unroll
      for (int mf = 0; mf < 2; ++mf)
#pragma unroll
        for (int nf = 0; nf < 2; ++nf) acc[mf][nf] = MFMA16(w0f[kc][nf], a[mf], acc[mf][nf]);
    }

    // H = relu(acc) -> Hl (own region; no hazard with A)
#pragma unroll
    for (int mf = 0; mf < 2; ++mf)
#pragma unroll
      for (int nf = 0; nf < 2; ++nf) {
        int row = mf * 16 + lr, nc = n0 + nf * 16 + lq * 4;
        bf16x4 p;
#pragma unroll
        for (int j = 0; j < 4; ++j) p[j] = (bf16)fmaxf(acc[mf][nf][j], 0.0f);
        int g = nc >> 3, gp = (g & 8) | ((g & 7) ^ (row & 7));
        *(bf16x4*)(Hl + row * 256 + gp * 16 + (nc & 7) * 2) = p;
      }
    // residual from A f-half -> acc2 init
    f32x4 acc2[2][2];
#pragma unroll
    for (int mf = 0; mf < 2; ++mf)
#pragma unroll
      for (int nf = 0; nf < 2; ++nf) {
        int row = mf * 16 + lr, nc = n0 + nf * 16 + lq * 4;
        int g = nc >> 3, gp = (g & 8) | ((g & 7) ^ (row & 7));
        bf16x4 res = *(const bf16x4*)(A + row * 512 + gp * 16 + (nc & 7) * 2);
#pragma unroll
        for (int j = 0; j < 4; ++j) acc2[mf][nf][j] = b1v[nf][j] + (float)res[j];
      }
    // #2: publishes Hl; per-wave lgkmcnt(0) drains all A reads (GEMM1+residual)
    // and prior-iter Hl reads (so the Hl writes above were safe)
    BAR_LGKM();

    // ---- GEMM2: relu(h @ W1 + b1 + f) ----
#pragma unroll
    for (int kc = 0; kc < 4; ++kc) {
      bf16x8 a[2];
#pragma unroll
      for (int mf = 0; mf < 2; ++mf) {
        int row = mf * 16 + lr, g = kc * 4 + lq;
        int gp = (g & 8) | ((g & 7) ^ (row & 7));
        a[mf] = *(const bf16x8*)(Hl + row * 256 + gp * 16);
      }
#pragma unroll
      for (int mf = 0; mf < 2; ++mf)
#pragma unroll
        for (int nf = 0; nf < 2; ++nf) acc2[mf][nf] = MFMA16(w1f[kc][nf], a[mf], acc2[mf][nf]);
    }
    // relu + repack f_next -> A f-half (A reads all drained at #2)
#pragma unroll
    for (int mf = 0; mf < 2; ++mf)
#pragma unroll
      for (int nf = 0; nf < 2; ++nf) {
        int row = mf * 16 + lr, nc = n0 + nf * 16 + lq * 4;
        bf16x4 p;
#pragma unroll
        for (int j = 0; j < 4; ++j) p[j] = (bf16)fmaxf(acc2[mf][nf][j], 0.0f);
        int g = nc >> 3, gp = (g & 8) | ((g & 7) ^ (row & 7));
        *(bf16x4*)(A + row * 512 + gp * 16 + (nc & 7) * 2) = p;
      }
    BAR_LGKM();  // #3: repack visible to all waves

    // copy-out: read to regs, barrier (frees buf for stage(t+2)), store
    bf16x8 v[2];
#pragma unroll
    for (int r = 0; r < 2; ++r) {
      int G = r * 256 + tid, row = G >> 4, gl = G & 15;
      int gp = (gl & 8) | ((gl & 7) ^ (row & 7));
      v[r] = *(const bf16x8*)(A + row * 512 + gp * 16);
    }
    BAR_LGKM();  // #4: all reads of At[t&1] done -> stage(t+2) may overwrite
    long mt0 = brow + (long)t * 32;
#pragma unroll
    for (int r = 0; r < 2; ++r) {
      int G = r * 256 + tid, row = G >> 4, gl = G & 15;
      *(bf16x8*)(f_out + (mt0 + row) * 128 + gl * 8) = v[r];
    }
#pragma unroll
    for (int r = 0; r < 4; ++r) par_s[r] = par_n[r];
  }
}

// ---------------- fc: out = f4 @ Wfc + bfc (fp32), pipelined x8 tiles ----------------
__global__ __launch_bounds__(256, 2) void fc_kernel(
    const bf16* __restrict__ f_in, const bf16* __restrict__ wt,
    const float* __restrict__ bias, float* __restrict__ out) {
  __shared__ alignas(128) char Ft[2][16384];  // [64][256B] bf16, swizzled, dbuf

  const int tid = threadIdx.x;
  const int lane = tid & 63, wv = tid >> 6;
  const int lr = lane & 15, lq = lane >> 4;
  const long brow = (long)blockIdx.x * 512;
  const int c0 = wv * 64;

  bf16x8 wf[4][4];
#pragma unroll
  for (int kc = 0; kc < 4; ++kc)
#pragma unroll
    for (int nf = 0; nf < 4; ++nf)
      wf[kc][nf] = *(const bf16x8*)(wt + (long)(c0 + nf * 16 + lr) * 128 + kc * 32 + lq * 8);
  f32x4 bv[4];
#pragma unroll
  for (int nf = 0; nf < 4; ++nf) bv[nf] = *(const f32x4*)(bias + c0 + nf * 16 + lq * 4);

  stage_ftile(f_in, brow, Ft[0], tid);  // stage(0): 4 VMEM

#pragma unroll 1
  for (int t = 0; t < 8; ++t) {
    stage_ftile(f_in, brow + (long)((t < 7) ? t + 1 : 7) * 64, Ft[(t + 1) & 1], tid);
    if (t == 0) { BAR_VM(4); } else { BAR_VM(20); }
    char* F = Ft[t & 1];

    f32x4 acc[4][4];
#pragma unroll
    for (int mf = 0; mf < 4; ++mf)
#pragma unroll
      for (int nf = 0; nf < 4; ++nf) acc[mf][nf] = bv[nf];
#pragma unroll
    for (int kc = 0; kc < 4; ++kc) {
      bf16x8 a[4];
#pragma unroll
      for (int mf = 0; mf < 4; ++mf) {
        int row = mf * 16 + lr, g = kc * 4 + lq;
        int gp = (g & 8) | ((g & 7) ^ (row & 7));
        a[mf] = *(const bf16x8*)(F + row * 256 + gp * 16);
      }
#pragma unroll
      for (int mf = 0; mf < 4; ++mf)
#pragma unroll
        for (int nf = 0; nf < 4; ++nf) acc[mf][nf] = MFMA16(wf[kc][nf], a[mf], acc[mf][nf]);
    }
    BAR_LGKM();  // all Ft[t&1] reads done -> stage(t+2) may overwrite

    long mt0 = brow + (long)t * 64;
#pragma unroll
    for (int mf = 0; mf < 4; ++mf)
#pragma unroll
      for (int nf = 0; nf < 4; ++nf) {
        long row = mt0 + mf * 16 + lr;
        int col = c0 + nf * 16 + lq * 4;
        *(f32x4*)(out + row * 256 + col) = acc[mf][nf];  // stores: S=16
      }
  }
}

extern "C" void kernel_launch(void* const* d_in, const int* in_sizes, int n_in,
                              void* d_out, int out_size, void* d_ws, size_t ws_size,
                              hipStream_t stream) {
  const float* data = (const float*)d_in[0];
  const float* W1_0 = (const float*)d_in[1];
  const float* b1_0 = (const float*)d_in[2];
  const float* W1_1 = (const float*)d_in[3];
  const float* b1_1 = (const float*)d_in[4];
  const float* W2_0 = (const float*)d_in[5];
  const float* b2_0 = (const float*)d_in[6];
  const float* W2_1 = (const float*)d_in[7];
  const float* b2_1 = (const float*)d_in[8];
  const float* W3_0 = (const float*)d_in[9];
  const float* b3_0 = (const float*)d_in[10];
  const float* W3_1 = (const float*)d_in[11];
  const float* b3_1 = (const float*)d_in[12];
  const float* W4_0 = (const float*)d_in[13];
  const float* b4_0 = (const float*)d_in[14];
  const float* W4_1 = (const float*)d_in[15];
  const float* b4_1 = (const float*)d_in[16];
  const float* Wfc = (const float*)d_in[17];
  const float* bfc = (const float*)d_in[18];

  bf16* wsb = (bf16*)d_ws;
  bf16* fA = (bf16*)((char*)d_ws + FA_BYTE);
  bf16* fB = (bf16*)((char*)d_ws + FB_BYTE);
  int* partab = (int*)((char*)d_ws + PT_BYTE);

  prep_kernel<<<(PREP_TOTAL + 255) / 256, 256, 0, stream>>>(W1_0, W1_1, W2_0, W2_1, W3_0, W3_1,
                                                            W4_0, W4_1, Wfc, wsb);
  pidx_kernel<<<2048, 256, 0, stream>>>(data, partab, fA, fB);
  stage1_kernel<<<1024, 256, 0, stream>>>(data, wsb + W10T, b1_0, wsb + W11T, b1_1, fA);
  resblock_kernel<<<1024, 256, 0, stream>>>(fA, wsb + W20T, b2_0, wsb + W21T, b2_1, partab, fB);
  resblock_kernel<<<1024, 256, 0, stream>>>(fB, wsb + W30T, b3_0, wsb + W31T, b3_1, partab, fA);
  resblock_kernel<<<1024, 256, 0, stream>>>(fA, wsb + W40T, b4_0, wsb + W41T, b4_1, partab, fB);
  fc_kernel<<<1024, 256, 0, stream>>>(fB, wsb + WFCT, bfc, (float*)d_out);
}

// Round 9
// 518.041 us; speedup vs baseline: 1.0260x; 1.0260x over previous
//
#include <hip/hip_runtime.h>
#include <hip/hip_bf16.h>

// BaseEntropyCoder: 4-layer residual MLP with parent-gather, bf16 MFMA pipeline.
// B=8, N=65536, D=128, OUT=256, M=524288 rows.
//
// R9 = R7 base (64-row rb tiles, 4 barriers) with rb's parent half taken out
// of LDS: stage only the f-half (16KB); GEMM1's parent operand is gathered
// per-lane straight to registers (L2/L3-hot; 4x-redundant reads are L2 hits).
// LDS 48KB/block. Entry barrier BAR_VM(4) ("all but 4 newest retired" --
// robust to compiler waits and spills).
// R5 lesson: same-iteration global loads only with compute cover before use.
// R6 lesson: LDS repack + coalesced copy-out; fc stays LDS-staged+pipelined.
// R8 lesson: 64-row tiles (32-row doubles fixed per-tile cost share).

typedef __bf16 bf16;
typedef bf16 bf16x8 __attribute__((ext_vector_type(8)));
typedef bf16 bf16x4 __attribute__((ext_vector_type(4)));
typedef float f32x4 __attribute__((ext_vector_type(4)));

#define MFMA16(a, b, c) __builtin_amdgcn_mfma_f32_16x16x32_bf16((a), (b), (c), 0, 0, 0)

#define BAR_LGKM() asm volatile("s_waitcnt lgkmcnt(0)\ns_barrier" ::: "memory")
#define BAR_VM(N) asm volatile("s_waitcnt vmcnt(" #N ")\ns_barrier" ::: "memory")

// ---- ws layout ----
#define ZB    0
#define W10T  128
#define W11T  4224
#define W20T  20608
#define W21T  53376
#define W30T  69760
#define W31T  102528
#define W40T  118912
#define W41T  151680
#define WFCT  168064
#define PREP_TOTAL 200832
#define FA_BYTE  524288
#define F_STRIDE 134221824   // 524289 rows * 256B, padded
#define FB_BYTE  (FA_BYTE + F_STRIDE)
#define PT_BYTE  (FA_BYTE + 2 * F_STRIDE)
#define ZROW_IDX 524288

__device__ __forceinline__ void gload16(const void* g, void* l) {
  __builtin_amdgcn_global_load_lds(
      (__attribute__((address_space(1))) void*)(g),
      (__attribute__((address_space(3))) void*)(l), 16, 0, 0);
}

// ---------------- weight prep: fp32 -> bf16, transposed ----------------
__global__ void prep_kernel(const float* __restrict__ W1_0, const float* __restrict__ W1_1,
                            const float* __restrict__ W2_0, const float* __restrict__ W2_1,
                            const float* __restrict__ W3_0, const float* __restrict__ W3_1,
                            const float* __restrict__ W4_0, const float* __restrict__ W4_1,
                            const float* __restrict__ Wfc, bf16* __restrict__ wsb) {
  int i = blockIdx.x * 256 + threadIdx.x;
  if (i < 128) { wsb[ZB + i] = (bf16)0.0f; return; }
  i -= 128;
  if (i < 4096) { int n = i >> 5, k = i & 31;
    wsb[W10T + i] = (bf16)((k < 6) ? W1_0[k * 128 + n] : 0.0f); return; }
  i -= 4096;
  if (i < 16384) { int n = i >> 7, k = i & 127; wsb[W11T + i] = (bf16)W1_1[k * 128 + n]; return; }
  i -= 16384;
  if (i < 32768) { int n = i >> 8, k = i & 255; wsb[W20T + i] = (bf16)W2_0[k * 128 + n]; return; }
  i -= 32768;
  if (i < 16384) { int n = i >> 7, k = i & 127; wsb[W21T + i] = (bf16)W2_1[k * 128 + n]; return; }
  i -= 16384;
  if (i < 32768) { int n = i >> 8, k = i & 255; wsb[W30T + i] = (bf16)W3_0[k * 128 + n]; return; }
  i -= 32768;
  if (i < 16384) { int n = i >> 7, k = i & 127; wsb[W31T + i] = (bf16)W3_1[k * 128 + n]; return; }
  i -= 16384;
  if (i < 32768) { int n = i >> 8, k = i & 255; wsb[W40T + i] = (bf16)W4_0[k * 128 + n]; return; }
  i -= 32768;
  if (i < 16384) { int n = i >> 7, k = i & 127; wsb[W41T + i] = (bf16)W4_1[k * 128 + n]; return; }
  i -= 16384;
  if (i < 32768) { int n = i >> 7, k = i & 127; wsb[WFCT + i] = (bf16)Wfc[k * 256 + n]; return; }
}

// ---------------- parent index table + zero-row init ----------------
__global__ void pidx_kernel(const float* __restrict__ data, int* __restrict__ partab,
                            bf16* __restrict__ fA, bf16* __restrict__ fB) {
  int m = blockIdx.x * 256 + threadIdx.x;
  float2 pr = *(const float2*)(data + (long)m * 8 + 6);
  partab[m] = (pr.y == 1.0f) ? ZROW_IDX : ((m & ~65535) + (int)pr.x);
  if (m < 128) {
    fA[(long)ZROW_IDX * 128 + m] = (bf16)0.0f;
    fB[(long)ZROW_IDX * 128 + m] = (bf16)0.0f;
  }
}

// ---- stage one 64-row f tile ([64][256B] swizzled): 4 gload16 per thread ----
__device__ __forceinline__ void stage_ftile(const bf16* __restrict__ f_in, long mt0,
                                            char* dst, int tid) {
  const int wv = tid >> 6;
#pragma unroll
  for (int r = 0; r < 4; ++r) {
    int G = r * 256 + tid, row = G >> 4, gl = G & 15;
    int g = (gl & 8) | ((gl & 7) ^ (row & 7));
    gload16(f_in + (mt0 + row) * 128 + g * 8, dst + (r * 256 + wv * 64) * 16);
  }
}

// ---------------- stage 1: f1 = relu(x@W1_0+b)@W1_1+b, pipelined x8 tiles ----
__global__ __launch_bounds__(256, 3) void stage1_kernel(
    const float* __restrict__ data, const bf16* __restrict__ w0t, const float* __restrict__ b0,
    const bf16* __restrict__ w1t, const float* __restrict__ b1, bf16* __restrict__ f_out) {
  __shared__ alignas(128) char Hb[2][16384];  // [64][256B] bf16, swizzled, dbuf

  const int tid = threadIdx.x;
  const int lane = tid & 63, wv = tid >> 6;
  const int lr = lane & 15, lq = lane >> 4;
  const long brow = (long)blockIdx.x * 512;
  const int n0 = wv * 32;

  bf16x8 w0f[2];
#pragma unroll
  for (int nf = 0; nf < 2; ++nf)
    w0f[nf] = *(const bf16x8*)(w0t + (long)(n0 + nf * 16 + lr) * 32 + lq * 8);
  bf16x8 w1f[4][2];
#pragma unroll
  for (int kc = 0; kc < 4; ++kc)
#pragma unroll
    for (int nf = 0; nf < 2; ++nf)
      w1f[kc][nf] = *(const bf16x8*)(w1t + (long)(n0 + nf * 16 + lr) * 128 + kc * 32 + lq * 8);
  f32x4 b0v[2], b1v[2];
#pragma unroll
  for (int nf = 0; nf < 2; ++nf) {
    b0v[nf] = *(const f32x4*)(b0 + n0 + nf * 16 + lq * 4);
    b1v[nf] = *(const f32x4*)(b1 + n0 + nf * 16 + lq * 4);
  }

  float4 xlo[4], xhi[4];
  if (lq == 0) {
#pragma unroll
    for (int mf = 0; mf < 4; ++mf) {
      const float* dp = data + (brow + mf * 16 + lr) * 8;
      xlo[mf] = *(const float4*)dp;
      xhi[mf] = *(const float4*)(dp + 4);
    }
  }

#pragma unroll 1
  for (int t = 0; t < 8; ++t) {
    bf16x8 xa[4];
#pragma unroll
    for (int mf = 0; mf < 4; ++mf) {
#pragma unroll
      for (int j = 0; j < 8; ++j) xa[mf][j] = (bf16)0.0f;
      if (lq == 0) {
#pragma unroll
        for (int j = 0; j < 4; ++j) xa[mf][j] = (bf16)xlo[mf][j];
        xa[mf][4] = (bf16)xhi[mf][0];
        xa[mf][5] = (bf16)xhi[mf][1];
      }
    }
    if (lq == 0) {  // prefetch next tile's rows
      long nb = brow + (long)((t < 7) ? t + 1 : 7) * 64;
#pragma unroll
      for (int mf = 0; mf < 4; ++mf) {
        const float* dp = data + (nb + mf * 16 + lr) * 8;
        xlo[mf] = *(const float4*)dp;
        xhi[mf] = *(const float4*)(dp + 4);
      }
    }

    // GEMM1 (K=32, 6 real)
    f32x4 acc[4][2];
#pragma unroll
    for (int mf = 0; mf < 4; ++mf)
#pragma unroll
      for (int nf = 0; nf < 2; ++nf) acc[mf][nf] = b0v[nf];
#pragma unroll
    for (int mf = 0; mf < 4; ++mf)
#pragma unroll
      for (int nf = 0; nf < 2; ++nf) acc[mf][nf] = MFMA16(w0f[nf], xa[mf], acc[mf][nf]);

    char* H = Hb[t & 1];
    // relu -> H
#pragma unroll
    for (int mf = 0; mf < 4; ++mf)
#pragma unroll
      for (int nf = 0; nf < 2; ++nf) {
        int row = mf * 16 + lr, nc = n0 + nf * 16 + lq * 4;
        bf16x4 p;
#pragma unroll
        for (int j = 0; j < 4; ++j) p[j] = (bf16)fmaxf(acc[mf][nf][j], 0.0f);
        int g = nc >> 3, gp = (g & 8) | ((g & 7) ^ (row & 7));
        *(bf16x4*)(H + row * 256 + gp * 16 + (nc & 7) * 2) = p;
      }
    BAR_LGKM();  // H published

    // GEMM2 (K=128)
    f32x4 acc2[4][2];
#pragma unroll
    for (int mf = 0; mf < 4; ++mf)
#pragma unroll
      for (int nf = 0; nf < 2; ++nf) acc2[mf][nf] = b1v[nf];
#pragma unroll
    for (int kc = 0; kc < 4; ++kc) {
      bf16x8 a[4];
#pragma unroll
      for (int mf = 0; mf < 4; ++mf) {
        int row = mf * 16 + lr, g = kc * 4 + lq;
        int gp = (g & 8) | ((g & 7) ^ (row & 7));
        a[mf] = *(const bf16x8*)(H + row * 256 + gp * 16);
      }
#pragma unroll
      for (int mf = 0; mf < 4; ++mf)
#pragma unroll
        for (int nf = 0; nf < 2; ++nf) acc2[mf][nf] = MFMA16(w1f[kc][nf], a[mf], acc2[mf][nf]);
    }
    BAR_LGKM();  // all H reads done

    // repack -> H
#pragma unroll
    for (int mf = 0; mf < 4; ++mf)
#pragma unroll
      for (int nf = 0; nf < 2; ++nf) {
        int row = mf * 16 + lr, nc = n0 + nf * 16 + lq * 4;
        bf16x4 p;
#pragma unroll
        for (int j = 0; j < 4; ++j) p[j] = (bf16)acc2[mf][nf][j];
        int g = nc >> 3, gp = (g & 8) | ((g & 7) ^ (row & 7));
        *(bf16x4*)(H + row * 256 + gp * 16 + (nc & 7) * 2) = p;
      }
    BAR_LGKM();  // f1 tile complete

    // coalesced copy-out
    long mt0 = brow + (long)t * 64;
#pragma unroll
    for (int r = 0; r < 4; ++r) {
      int G = r * 256 + tid, row = G >> 4, gl = G & 15;
      int gp = (gl & 8) | ((gl & 7) ^ (row & 7));
      bf16x8 v = *(const bf16x8*)(H + row * 256 + gp * 16);
      *(bf16x8*)(f_out + (mt0 + row) * 128 + gl * 8) = v;
    }
  }
}

// ------- residual block, 64-row tiles x16, f-half staged + reg-gathered par -------
__global__ __launch_bounds__(256, 2) void resblock_kernel(
    const bf16* __restrict__ f_in, const bf16* __restrict__ w0t, const float* __restrict__ b0,
    const bf16* __restrict__ w1t, const float* __restrict__ b1,
    const int* __restrict__ partab, bf16* __restrict__ f_out) {
  // At: [64 rows][256B] f tile, swizzled, dbuf. Hl: [64][256B] own region.
  __shared__ alignas(128) char At[2][16384];
  __shared__ alignas(128) char Hl[16384];

  const int tid = threadIdx.x;
  const int lane = tid & 63, wv = tid >> 6;
  const int lr = lane & 15, lq = lane >> 4;
  const long brow = (long)blockIdx.x * 1024;
  const int n0 = wv * 32;

  // resident weights + biases
  bf16x8 w0f[8][2];
#pragma unroll
  for (int kc = 0; kc < 8; ++kc)
#pragma unroll
    for (int nf = 0; nf < 2; ++nf)
      w0f[kc][nf] = *(const bf16x8*)(w0t + (long)(n0 + nf * 16 + lr) * 256 + kc * 32 + lq * 8);
  bf16x8 w1f[4][2];
#pragma unroll
  for (int kc = 0; kc < 4; ++kc)
#pragma unroll
    for (int nf = 0; nf < 2; ++nf)
      w1f[kc][nf] = *(const bf16x8*)(w1t + (long)(n0 + nf * 16 + lr) * 128 + kc * 32 + lq * 8);
  f32x4 b0v[2], b1v[2];
#pragma unroll
  for (int nf = 0; nf < 2; ++nf) {
    b0v[nf] = *(const f32x4*)(b0 + n0 + nf * 16 + lq * 4);
    b1v[nf] = *(const f32x4*)(b1 + n0 + nf * 16 + lq * 4);
  }

  stage_ftile(f_in, brow, At[0], tid);  // stage(0): 4 gload16

#pragma unroll 1
  for (int t = 0; t < 16; ++t) {
    // stage(t+1) f-half (dummy re-stage of tile 15 at t=15)
    stage_ftile(f_in, brow + (long)((t < 15) ? t + 1 : 15) * 64, At[(t + 1) & 1], tid);
    // entry: all but the 4 newest (stage(t+1)) retired -> stage(t) complete.
    BAR_VM(4);
    char* A = At[t & 1];
    long mt0 = brow + (long)t * 64;

    // ---- parent operand: per-lane gather straight to registers ----
    int pidxv[4];
#pragma unroll
    for (int mf = 0; mf < 4; ++mf) pidxv[mf] = partab[mt0 + mf * 16 + lr];
    bf16x8 pa[4][4];  // [kc2][mf], par K rows 128..255
#pragma unroll
    for (int kc2 = 0; kc2 < 4; ++kc2)
#pragma unroll
      for (int mf = 0; mf < 4; ++mf)
        pa[kc2][mf] = *(const bf16x8*)(f_in + (long)pidxv[mf] * 128 + kc2 * 32 + lq * 8);

    // ---- GEMM1: h = relu([f|par] @ W0 + b0) ----
    f32x4 acc[4][2];
#pragma unroll
    for (int mf = 0; mf < 4; ++mf)
#pragma unroll
      for (int nf = 0; nf < 2; ++nf) acc[mf][nf] = b0v[nf];
    // f-half from LDS (covers the gather latency)
#pragma unroll
    for (int kc = 0; kc < 4; ++kc) {
      bf16x8 a[4];
#pragma unroll
      for (int mf = 0; mf < 4; ++mf) {
        int row = mf * 16 + lr, g = kc * 4 + lq;
        int gp = (g & 8) | ((g & 7) ^ (row & 7));
        a[mf] = *(const bf16x8*)(A + row * 256 + gp * 16);
      }
#pragma unroll
      for (int mf = 0; mf < 4; ++mf)
#pragma unroll
        for (int nf = 0; nf < 2; ++nf) acc[mf][nf] = MFMA16(w0f[kc][nf], a[mf], acc[mf][nf]);
    }
    // par-half from registers
#pragma unroll
    for (int kc2 = 0; kc2 < 4; ++kc2)
#pragma unroll
      for (int mf = 0; mf < 4; ++mf)
#pragma unroll
        for (int nf = 0; nf < 2; ++nf)
          acc[mf][nf] = MFMA16(w0f[4 + kc2][nf], pa[kc2][mf], acc[mf][nf]);

    // H = relu(acc) -> Hl
#pragma unroll
    for (int mf = 0; mf < 4; ++mf)
#pragma unroll
      for (int nf = 0; nf < 2; ++nf) {
        int row = mf * 16 + lr, nc = n0 + nf * 16 + lq * 4;
        bf16x4 p;
#pragma unroll
        for (int j = 0; j < 4; ++j) p[j] = (bf16)fmaxf(acc[mf][nf][j], 0.0f);
        int g = nc >> 3, gp = (g & 8) | ((g & 7) ^ (row & 7));
        *(bf16x4*)(Hl + row * 256 + gp * 16 + (nc & 7) * 2) = p;
      }
    // residual from A -> acc2 init
    f32x4 acc2[4][2];
#pragma unroll
    for (int mf = 0; mf < 4; ++mf)
#pragma unroll
      for (int nf = 0; nf < 2; ++nf) {
        int row = mf * 16 + lr, nc = n0 + nf * 16 + lq * 4;
        int g = nc >> 3, gp = (g & 8) | ((g & 7) ^ (row & 7));
        bf16x4 res = *(const bf16x4*)(A + row * 256 + gp * 16 + (nc & 7) * 2);
#pragma unroll
        for (int j = 0; j < 4; ++j) acc2[mf][nf][j] = b1v[nf][j] + (float)res[j];
      }
    // #2: publishes Hl; per-wave lgkmcnt(0) drains all A reads and prior Hl reads
    BAR_LGKM();

    // ---- GEMM2: relu(h @ W1 + b1 + f) ----
#pragma unroll
    for (int kc = 0; kc < 4; ++kc) {
      bf16x8 a[4];
#pragma unroll
      for (int mf = 0; mf < 4; ++mf) {
        int row = mf * 16 + lr, g = kc * 4 + lq;
        int gp = (g & 8) | ((g & 7) ^ (row & 7));
        a[mf] = *(const bf16x8*)(Hl + row * 256 + gp * 16);
      }
#pragma unroll
      for (int mf = 0; mf < 4; ++mf)
#pragma unroll
        for (int nf = 0; nf < 2; ++nf) acc2[mf][nf] = MFMA16(w1f[kc][nf], a[mf], acc2[mf][nf]);
    }
    // relu + repack f_next -> A (A reads drained at #2)
#pragma unroll
    for (int mf = 0; mf < 4; ++mf)
#pragma unroll
      for (int nf = 0; nf < 2; ++nf) {
        int row = mf * 16 + lr, nc = n0 + nf * 16 + lq * 4;
        bf16x4 p;
#pragma unroll
        for (int j = 0; j < 4; ++j) p[j] = (bf16)fmaxf(acc2[mf][nf][j], 0.0f);
        int g = nc >> 3, gp = (g & 8) | ((g & 7) ^ (row & 7));
        *(bf16x4*)(A + row * 256 + gp * 16 + (nc & 7) * 2) = p;
      }
    BAR_LGKM();  // #3: repack visible to all waves

    // copy-out: read to regs, barrier (frees buf for stage(t+2)), store
    bf16x8 v[4];
#pragma unroll
    for (int r = 0; r < 4; ++r) {
      int G = r * 256 + tid, row = G >> 4, gl = G & 15;
      int gp = (gl & 8) | ((gl & 7) ^ (row & 7));
      v[r] = *(const bf16x8*)(A + row * 256 + gp * 16);
    }
    BAR_LGKM();  // #4: all reads of At[t&1] done -> stage(t+2) may overwrite
#pragma unroll
    for (int r = 0; r < 4; ++r) {
      int G = r * 256 + tid, row = G >> 4, gl = G & 15;
      *(bf16x8*)(f_out + (mt0 + row) * 128 + gl * 8) = v[r];
    }
  }
}

// ---------------- fc: out = f4 @ Wfc + bfc (fp32), pipelined x8 tiles ----------------
__global__ __launch_bounds__(256, 2) void fc_kernel(
    const bf16* __restrict__ f_in, const bf16* __restrict__ wt,
    const float* __restrict__ bias, float* __restrict__ out) {
  __shared__ alignas(128) char Ft[2][16384];  // [64][256B] bf16, swizzled, dbuf

  const int tid = threadIdx.x;
  const int lane = tid & 63, wv = tid >> 6;
  const int lr = lane & 15, lq = lane >> 4;
  const long brow = (long)blockIdx.x * 512;
  const int c0 = wv * 64;

  bf16x8 wf[4][4];
#pragma unroll
  for (int kc = 0; kc < 4; ++kc)
#pragma unroll
    for (int nf = 0; nf < 4; ++nf)
      wf[kc][nf] = *(const bf16x8*)(wt + (long)(c0 + nf * 16 + lr) * 128 + kc * 32 + lq * 8);
  f32x4 bv[4];
#pragma unroll
  for (int nf = 0; nf < 4; ++nf) bv[nf] = *(const f32x4*)(bias + c0 + nf * 16 + lq * 4);

  stage_ftile(f_in, brow, Ft[0], tid);  // stage(0): 4 VMEM

#pragma unroll 1
  for (int t = 0; t < 8; ++t) {
    stage_ftile(f_in, brow + (long)((t < 7) ? t + 1 : 7) * 64, Ft[(t + 1) & 1], tid);
    if (t == 0) { BAR_VM(4); } else { BAR_VM(20); }
    char* F = Ft[t & 1];

    f32x4 acc[4][4];
#pragma unroll
    for (int mf = 0; mf < 4; ++mf)
#pragma unroll
      for (int nf = 0; nf < 4; ++nf) acc[mf][nf] = bv[nf];
#pragma unroll
    for (int kc = 0; kc < 4; ++kc) {
      bf16x8 a[4];
#pragma unroll
      for (int mf = 0; mf < 4; ++mf) {
        int row = mf * 16 + lr, g = kc * 4 + lq;
        int gp = (g & 8) | ((g & 7) ^ (row & 7));
        a[mf] = *(const bf16x8*)(F + row * 256 + gp * 16);
      }
#pragma unroll
      for (int mf = 0; mf < 4; ++mf)
#pragma unroll
        for (int nf = 0; nf < 4; ++nf) acc[mf][nf] = MFMA16(wf[kc][nf], a[mf], acc[mf][nf]);
    }
    BAR_LGKM();  // all Ft[t&1] reads done -> stage(t+2) may overwrite

    long mt0 = brow + (long)t * 64;
#pragma unroll
    for (int mf = 0; mf < 4; ++mf)
#pragma unroll
      for (int nf = 0; nf < 4; ++nf) {
        long row = mt0 + mf * 16 + lr;
        int col = c0 + nf * 16 + lq * 4;
        *(f32x4*)(out + row * 256 + col) = acc[mf][nf];
      }
  }
}

extern "C" void kernel_launch(void* const* d_in, const int* in_sizes, int n_in,
                              void* d_out, int out_size, void* d_ws, size_t ws_size,
                              hipStream_t stream) {
  const float* data = (const float*)d_in[0];
  const float* W1_0 = (const float*)d_in[1];
  const float* b1_0 = (const float*)d_in[2];
  const float* W1_1 = (const float*)d_in[3];
  const float* b1_1 = (const float*)d_in[4];
  const float* W2_0 = (const float*)d_in[5];
  const float* b2_0 = (const float*)d_in[6];
  const float* W2_1 = (const float*)d_in[7];
  const float* b2_1 = (const float*)d_in[8];
  const float* W3_0 = (const float*)d_in[9];
  const float* b3_0 = (const float*)d_in[10];
  const float* W3_1 = (const float*)d_in[11];
  const float* b3_1 = (const float*)d_in[12];
  const float* W4_0 = (const float*)d_in[13];
  const float* b4_0 = (const float*)d_in[14];
  const float* W4_1 = (const float*)d_in[15];
  const float* b4_1 = (const float*)d_in[16];
  const float* Wfc = (const float*)d_in[17];
  const float* bfc = (const float*)d_in[18];

  bf16* wsb = (bf16*)d_ws;
  bf16* fA = (bf16*)((char*)d_ws + FA_BYTE);
  bf16* fB = (bf16*)((char*)d_ws + FB_BYTE);
  int* partab = (int*)((char*)d_ws + PT_BYTE);

  prep_kernel<<<(PREP_TOTAL + 255) / 256, 256, 0, stream>>>(W1_0, W1_1, W2_0, W2_1, W3_0, W3_1,
                                                            W4_0, W4_1, Wfc, wsb);
  pidx_kernel<<<2048, 256, 0, stream>>>(data, partab, fA, fB);
  stage1_kernel<<<1024, 256, 0, stream>>>(data, wsb + W10T, b1_0, wsb + W11T, b1_1, fA);
  resblock_kernel<<<512, 256, 0, stream>>>(fA, wsb + W20T, b2_0, wsb + W21T, b2_1, partab, fB);
  resblock_kernel<<<512, 256, 0, stream>>>(fB, wsb + W30T, b3_0, wsb + W31T, b3_1, partab, fA);
  resblock_kernel<<<512, 256, 0, stream>>>(fA, wsb + W40T, b4_0, wsb + W41T, b4_1, partab, fB);
  fc_kernel<<<1024, 256, 0, stream>>>(fB, wsb + WFCT, bfc, (float*)d_out);
}

// Round 10
// 423.756 us; speedup vs baseline: 1.2543x; 1.2225x over previous
//
#include <hip/hip_runtime.h>
#include <hip/hip_bf16.h>

// BaseEntropyCoder: 4-layer residual MLP with parent-gather, bf16 MFMA pipeline.
// B=8, N=65536, D=128, OUT=256, M=524288 rows.
//
// R10 = R4 champion (427us) verbatim, with prep+pidx merged into one kernel.
// Structure: per-block multi-tile streaming pipeline; LDS double-buffered;
// STAGE(t+1) via global_load_lds issued before computing tile t, waited with
// COUNTED vmcnt (never 0); raw lgkmcnt(0)+s_barrier barriers.
//
// Hard-won rules (R5-R9):
//  - No global load issued after STAGE(t+1) may be consumed mid-loop: waiting
//    for it drains the prefetch (vmcnt is a FIFO). Weights/bias load ONCE
//    before the tile loop.
//  - Keep LDS repack + coalesced 16B/lane copy-out (scattered 8B fragment
//    stores regress ~15-25us/kernel).
//  - 64-row tiles (32-row doubles the per-tile fixed-cost share: +100us).
//  - rb needs ~220 VGPR -> 2 waves/SIMD is a hard wall; 3 blocks/CU configs
//    force weight reloads and regress.

typedef __bf16 bf16;
typedef bf16 bf16x8 __attribute__((ext_vector_type(8)));
typedef bf16 bf16x4 __attribute__((ext_vector_type(4)));
typedef float f32x4 __attribute__((ext_vector_type(4)));

#define MFMA16(a, b, c) __builtin_amdgcn_mfma_f32_16x16x32_bf16((a), (b), (c), 0, 0, 0)

#define BAR_LGKM() asm volatile("s_waitcnt lgkmcnt(0)\ns_barrier" ::: "memory")
#define BAR_VM(N) asm volatile("s_waitcnt vmcnt(" #N ")\ns_barrier" ::: "memory")

// ---- ws layout ----
#define ZB    0
#define W10T  128
#define W11T  4224
#define W20T  20608
#define W21T  53376
#define W30T  69760
#define W31T  102528
#define W40T  118912
#define W41T  151680
#define WFCT  168064
#define PREP_TOTAL 200832
#define FA_BYTE  524288
#define F_STRIDE 134221824   // 524289 rows * 256B, padded
#define FB_BYTE  (FA_BYTE + F_STRIDE)
#define PT_BYTE  (FA_BYTE + 2 * F_STRIDE)
#define ZROW_IDX 524288

__device__ __forceinline__ void gload16(const void* g, void* l) {
  __builtin_amdgcn_global_load_lds(
      (__attribute__((address_space(1))) void*)(g),
      (__attribute__((address_space(3))) void*)(l), 16, 0, 0);
}

// -------- fused prep: weights fp32->bf16 transposed + parent table + zero rows --------
__global__ void prep_pidx_kernel(const float* __restrict__ W1_0, const float* __restrict__ W1_1,
                                 const float* __restrict__ W2_0, const float* __restrict__ W2_1,
                                 const float* __restrict__ W3_0, const float* __restrict__ W3_1,
                                 const float* __restrict__ W4_0, const float* __restrict__ W4_1,
                                 const float* __restrict__ Wfc, bf16* __restrict__ wsb,
                                 const float* __restrict__ data, int* __restrict__ partab,
                                 bf16* __restrict__ fA, bf16* __restrict__ fB) {
  int m = blockIdx.x * 256 + threadIdx.x;  // [0, 524288)
  // parent index table
  float2 pr = *(const float2*)(data + (long)m * 8 + 6);
  partab[m] = (pr.y == 1.0f) ? ZROW_IDX : ((m & ~65535) + (int)pr.x);
  if (m < 128) {
    fA[(long)ZROW_IDX * 128 + m] = (bf16)0.0f;
    fB[(long)ZROW_IDX * 128 + m] = (bf16)0.0f;
  }
  // weight prep
  int i = m;
  if (i >= PREP_TOTAL) return;
  if (i < 128) { wsb[ZB + i] = (bf16)0.0f; return; }
  i -= 128;
  if (i < 4096) { int n = i >> 5, k = i & 31;
    wsb[W10T + i] = (bf16)((k < 6) ? W1_0[k * 128 + n] : 0.0f); return; }
  i -= 4096;
  if (i < 16384) { int n = i >> 7, k = i & 127; wsb[W11T + i] = (bf16)W1_1[k * 128 + n]; return; }
  i -= 16384;
  if (i < 32768) { int n = i >> 8, k = i & 255; wsb[W20T + i] = (bf16)W2_0[k * 128 + n]; return; }
  i -= 32768;
  if (i < 16384) { int n = i >> 7, k = i & 127; wsb[W21T + i] = (bf16)W2_1[k * 128 + n]; return; }
  i -= 16384;
  if (i < 32768) { int n = i >> 8, k = i & 255; wsb[W30T + i] = (bf16)W3_0[k * 128 + n]; return; }
  i -= 32768;
  if (i < 16384) { int n = i >> 7, k = i & 127; wsb[W31T + i] = (bf16)W3_1[k * 128 + n]; return; }
  i -= 16384;
  if (i < 32768) { int n = i >> 8, k = i & 255; wsb[W40T + i] = (bf16)W4_0[k * 128 + n]; return; }
  i -= 32768;
  if (i < 16384) { int n = i >> 7, k = i & 127; wsb[W41T + i] = (bf16)W4_1[k * 128 + n]; return; }
  i -= 16384;
  if (i < 32768) { int n = i >> 7, k = i & 127; wsb[WFCT + i] = (bf16)Wfc[k * 256 + n]; return; }
}

// ---- stage one 64-row concat(f,parent) tile: 16 VMEM ops (8 idx + 8 lds) ----
__device__ __forceinline__ void stage_tile(const bf16* __restrict__ f_in,
                                           const int* __restrict__ partab, long mt0,
                                           char* dst, int tid) {
  const int wv = tid >> 6;
  int par[8];
#pragma unroll
  for (int r = 0; r < 8; ++r) par[r] = partab[mt0 + r * 8 + (tid >> 5)];
#pragma unroll
  for (int r = 0; r < 8; ++r) {
    int row = r * 8 + (tid >> 5);
    int gp = tid & 31;
    int g = (gp & 8) | ((gp & 7) ^ (row & 7));
    const bf16* base = (gp < 16) ? (f_in + (mt0 + row) * 128) : (f_in + (long)par[r] * 128);
    gload16(base + g * 8, dst + (r * 256 + wv * 64) * 16);
  }
}

// ---- stage one 64-row f tile (fc): 4 VMEM ops ----
__device__ __forceinline__ void stage_ftile(const bf16* __restrict__ f_in, long mt0,
                                            char* dst, int tid) {
  const int wv = tid >> 6;
#pragma unroll
  for (int r = 0; r < 4; ++r) {
    int G = r * 256 + tid, row = G >> 4, gl = G & 15;
    int g = (gl & 8) | ((gl & 7) ^ (row & 7));
    gload16(f_in + (mt0 + row) * 128 + g * 8, dst + (r * 256 + wv * 64) * 16);
  }
}

// ---------------- stage 1: f1 = relu(x@W1_0+b)@W1_1+b, pipelined x8 tiles ----
__global__ __launch_bounds__(256, 3) void stage1_kernel(
    const float* __restrict__ data, const bf16* __restrict__ w0t, const float* __restrict__ b0,
    const bf16* __restrict__ w1t, const float* __restrict__ b1, bf16* __restrict__ f_out) {
  __shared__ alignas(128) char Hb[2][16384];  // [64][256B] bf16, swizzled, dbuf

  const int tid = threadIdx.x;
  const int lane = tid & 63, wv = tid >> 6;
  const int lr = lane & 15, lq = lane >> 4;
  const long brow = (long)blockIdx.x * 512;
  const int n0 = wv * 32;

  bf16x8 w0f[2];
#pragma unroll
  for (int nf = 0; nf < 2; ++nf)
    w0f[nf] = *(const bf16x8*)(w0t + (long)(n0 + nf * 16 + lr) * 32 + lq * 8);
  bf16x8 w1f[4][2];
#pragma unroll
  for (int kc = 0; kc < 4; ++kc)
#pragma unroll
    for (int nf = 0; nf < 2; ++nf)
      w1f[kc][nf] = *(const bf16x8*)(w1t + (long)(n0 + nf * 16 + lr) * 128 + kc * 32 + lq * 8);
  f32x4 b0v[2], b1v[2];
#pragma unroll
  for (int nf = 0; nf < 2; ++nf) {
    b0v[nf] = *(const f32x4*)(b0 + n0 + nf * 16 + lq * 4);
    b1v[nf] = *(const f32x4*)(b1 + n0 + nf * 16 + lq * 4);
  }

  float4 xlo[4], xhi[4];
  if (lq == 0) {
#pragma unroll
    for (int mf = 0; mf < 4; ++mf) {
      const float* dp = data + (brow + mf * 16 + lr) * 8;
      xlo[mf] = *(const float4*)dp;
      xhi[mf] = *(const float4*)(dp + 4);
    }
  }

#pragma unroll 1
  for (int t = 0; t < 8; ++t) {
    // build A-frags from current regs
    bf16x8 xa[4];
#pragma unroll
    for (int mf = 0; mf < 4; ++mf) {
#pragma unroll
      for (int j = 0; j < 8; ++j) xa[mf][j] = (bf16)0.0f;
      if (lq == 0) {
#pragma unroll
        for (int j = 0; j < 4; ++j) xa[mf][j] = (bf16)xlo[mf][j];
        xa[mf][4] = (bf16)xhi[mf][0];
        xa[mf][5] = (bf16)xhi[mf][1];
      }
    }
    // prefetch next tile's rows
    if (lq == 0) {
      long nb = brow + (long)((t < 7) ? t + 1 : 7) * 64;
#pragma unroll
      for (int mf = 0; mf < 4; ++mf) {
        const float* dp = data + (nb + mf * 16 + lr) * 8;
        xlo[mf] = *(const float4*)dp;
        xhi[mf] = *(const float4*)(dp + 4);
      }
    }

    // GEMM1 (K=32, 6 real)
    f32x4 acc[4][2];
#pragma unroll
    for (int mf = 0; mf < 4; ++mf)
#pragma unroll
      for (int nf = 0; nf < 2; ++nf) acc[mf][nf] = b0v[nf];
#pragma unroll
    for (int mf = 0; mf < 4; ++mf)
#pragma unroll
      for (int nf = 0; nf < 2; ++nf) acc[mf][nf] = MFMA16(w0f[nf], xa[mf], acc[mf][nf]);

    char* H = Hb[t & 1];
    // relu -> H
#pragma unroll
    for (int mf = 0; mf < 4; ++mf)
#pragma unroll
      for (int nf = 0; nf < 2; ++nf) {
        int row = mf * 16 + lr, nc = n0 + nf * 16 + lq * 4;
        bf16x4 p;
#pragma unroll
        for (int j = 0; j < 4; ++j) p[j] = (bf16)fmaxf(acc[mf][nf][j], 0.0f);
        int g = nc >> 3, gp = (g & 8) | ((g & 7) ^ (row & 7));
        *(bf16x4*)(H + row * 256 + gp * 16 + (nc & 7) * 2) = p;
      }
    BAR_LGKM();  // H published

    // GEMM2 (K=128)
    f32x4 acc2[4][2];
#pragma unroll
    for (int mf = 0; mf < 4; ++mf)
#pragma unroll
      for (int nf = 0; nf < 2; ++nf) acc2[mf][nf] = b1v[nf];
#pragma unroll
    for (int kc = 0; kc < 4; ++kc) {
      bf16x8 a[4];
#pragma unroll
      for (int mf = 0; mf < 4; ++mf) {
        int row = mf * 16 + lr, g = kc * 4 + lq;
        int gp = (g & 8) | ((g & 7) ^ (row & 7));
        a[mf] = *(const bf16x8*)(H + row * 256 + gp * 16);
      }
#pragma unroll
      for (int mf = 0; mf < 4; ++mf)
#pragma unroll
        for (int nf = 0; nf < 2; ++nf) acc2[mf][nf] = MFMA16(w1f[kc][nf], a[mf], acc2[mf][nf]);
    }
    BAR_LGKM();  // all H reads done

    // repack -> H
#pragma unroll
    for (int mf = 0; mf < 4; ++mf)
#pragma unroll
      for (int nf = 0; nf < 2; ++nf) {
        int row = mf * 16 + lr, nc = n0 + nf * 16 + lq * 4;
        bf16x4 p;
#pragma unroll
        for (int j = 0; j < 4; ++j) p[j] = (bf16)acc2[mf][nf][j];
        int g = nc >> 3, gp = (g & 8) | ((g & 7) ^ (row & 7));
        *(bf16x4*)(H + row * 256 + gp * 16 + (nc & 7) * 2) = p;
      }
    BAR_LGKM();  // f1 tile complete

    // coalesced copy-out
    long mt0 = brow + (long)t * 64;
#pragma unroll
    for (int r = 0; r < 4; ++r) {
      int G = r * 256 + tid, row = G >> 4, gl = G & 15;
      int gp = (gl & 8) | ((gl & 7) ^ (row & 7));
      bf16x8 v = *(const bf16x8*)(H + row * 256 + gp * 16);
      *(bf16x8*)(f_out + (mt0 + row) * 128 + gl * 8) = v;
    }
  }
}

// ---------------- residual block, pipelined x16 tiles ----------------
__global__ __launch_bounds__(256, 2) void resblock_kernel(
    const bf16* __restrict__ f_in, const bf16* __restrict__ w0t, const float* __restrict__ b0,
    const bf16* __restrict__ w1t, const float* __restrict__ b1,
    const int* __restrict__ partab, bf16* __restrict__ f_out) {
  // At[k]: [64 rows][512 B]: granules 0-15 f (residual), 16-31 parent -> H overlay
  __shared__ alignas(128) char At[2][32768];

  const int tid = threadIdx.x;
  const int lane = tid & 63, wv = tid >> 6;
  const int lr = lane & 15, lq = lane >> 4;
  const long brow = (long)blockIdx.x * 1024;
  const int n0 = wv * 32;

  // resident weights + biases
  bf16x8 w0f[8][2];
#pragma unroll
  for (int kc = 0; kc < 8; ++kc)
#pragma unroll
    for (int nf = 0; nf < 2; ++nf)
      w0f[kc][nf] = *(const bf16x8*)(w0t + (long)(n0 + nf * 16 + lr) * 256 + kc * 32 + lq * 8);
  bf16x8 w1f[4][2];
#pragma unroll
  for (int kc = 0; kc < 4; ++kc)
#pragma unroll
    for (int nf = 0; nf < 2; ++nf)
      w1f[kc][nf] = *(const bf16x8*)(w1t + (long)(n0 + nf * 16 + lr) * 128 + kc * 32 + lq * 8);
  f32x4 b0v[2], b1v[2];
#pragma unroll
  for (int nf = 0; nf < 2; ++nf) {
    b0v[nf] = *(const f32x4*)(b0 + n0 + nf * 16 + lq * 4);
    b1v[nf] = *(const f32x4*)(b1 + n0 + nf * 16 + lq * 4);
  }

  stage_tile(f_in, partab, brow, At[0], tid);  // stage(0): 16 VMEM

#pragma unroll 1
  for (int t = 0; t < 16; ++t) {
    // prefetch stage(t+1) (dummy re-stage of tile 15 at t=15)
    stage_tile(f_in, partab, brow + (long)((t < 15) ? t + 1 : 15) * 64, At[(t + 1) & 1], tid);
    // entry: tile t's 16 loads retired; newer ops stay in flight
    if (t == 0) { BAR_VM(16); } else { BAR_VM(20); }
    char* A = At[t & 1];

    // ---- GEMM1: h = relu([f|par] @ W0 + b0) ----
    f32x4 acc[4][2];
#pragma unroll
    for (int mf = 0; mf < 4; ++mf)
#pragma unroll
      for (int nf = 0; nf < 2; ++nf) acc[mf][nf] = b0v[nf];
#pragma unroll
    for (int kc = 0; kc < 8; ++kc) {
      bf16x8 a[4];
#pragma unroll
      for (int mf = 0; mf < 4; ++mf) {
        int row = mf * 16 + lr, g = kc * 4 + lq;
        int gp = (g & 24) | ((g & 7) ^ (row & 7));
        a[mf] = *(const bf16x8*)(A + row * 512 + gp * 16);
      }
#pragma unroll
      for (int mf = 0; mf < 4; ++mf)
#pragma unroll
        for (int nf = 0; nf < 2; ++nf) acc[mf][nf] = MFMA16(w0f[kc][nf], a[mf], acc[mf][nf]);
    }
    BAR_LGKM();  // (2) all parent-half reads done

    // ---- H = relu(acc) -> overlay; residual reads f-half (disjoint) ----
#pragma unroll
    for (int mf = 0; mf < 4; ++mf)
#pragma unroll
      for (int nf = 0; nf < 2; ++nf) {
        int row = mf * 16 + lr, nc = n0 + nf * 16 + lq * 4;
        bf16x4 p;
#pragma unroll
        for (int j = 0; j < 4; ++j) p[j] = (bf16)fmaxf(acc[mf][nf][j], 0.0f);
        int g = nc >> 3, gp = (g & 8) | ((g & 7) ^ (row & 7));
        *(bf16x4*)(A + row * 512 + 256 + gp * 16 + (nc & 7) * 2) = p;
      }
    f32x4 acc2[4][2];
#pragma unroll
    for (int mf = 0; mf < 4; ++mf)
#pragma unroll
      for (int nf = 0; nf < 2; ++nf) {
        int row = mf * 16 + lr, nc = n0 + nf * 16 + lq * 4;
        int g = nc >> 3, gp = (g & 8) | ((g & 7) ^ (row & 7));
        bf16x4 res = *(const bf16x4*)(A + row * 512 + gp * 16 + (nc & 7) * 2);
#pragma unroll
        for (int j = 0; j < 4; ++j) acc2[mf][nf][j] = b1v[nf][j] + (float)res[j];
      }
    BAR_LGKM();  // (3) H published

    // ---- GEMM2: relu(h @ W1 + b1 + f) ----
#pragma unroll
    for (int kc = 0; kc < 4; ++kc) {
      bf16x8 a[4];
#pragma unroll
      for (int mf = 0; mf < 4; ++mf) {
        int row = mf * 16 + lr, g = kc * 4 + lq;
        int gp = (g & 8) | ((g & 7) ^ (row & 7));
        a[mf] = *(const bf16x8*)(A + row * 512 + 256 + gp * 16);
      }
#pragma unroll
      for (int mf = 0; mf < 4; ++mf)
#pragma unroll
        for (int nf = 0; nf < 2; ++nf) acc2[mf][nf] = MFMA16(w1f[kc][nf], a[mf], acc2[mf][nf]);
    }
    // repack f_next into f-half (own columns; H-reads are parent-half,
    // residual f-half reads finished before (3))
#pragma unroll
    for (int mf = 0; mf < 4; ++mf)
#pragma unroll
      for (int nf = 0; nf < 2; ++nf) {
        int row = mf * 16 + lr, nc = n0 + nf * 16 + lq * 4;
        bf16x4 p;
#pragma unroll
        for (int j = 0; j < 4; ++j) p[j] = (bf16)fmaxf(acc2[mf][nf][j], 0.0f);
        int g = nc >> 3, gp = (g & 8) | ((g & 7) ^ (row & 7));
        *(bf16x4*)(A + row * 512 + gp * 16 + (nc & 7) * 2) = p;
      }
    BAR_LGKM();  // (4) f_next complete

    // copy-out: read to regs, barrier (frees buf for stage(t+2)), store
    bf16x8 v[4];
#pragma unroll
    for (int r = 0; r < 4; ++r) {
      int G = r * 256 + tid, row = G >> 4, gl = G & 15;
      int gp = (gl & 8) | ((gl & 7) ^ (row & 7));
      v[r] = *(const bf16x8*)(A + row * 512 + gp * 16);
    }
    BAR_LGKM();  // (5) all reads of At[t&1] done
    long mt0 = brow + (long)t * 64;
#pragma unroll
    for (int r = 0; r < 4; ++r) {
      int G = r * 256 + tid, row = G >> 4, gl = G & 15;
      *(bf16x8*)(f_out + (mt0 + row) * 128 + gl * 8) = v[r];  // stores: S=4
    }
  }
}

// ---------------- fc: out = f4 @ Wfc + bfc (fp32), pipelined x8 tiles ----------------
__global__ __launch_bounds__(256, 2) void fc_kernel(
    const bf16* __restrict__ f_in, const bf16* __restrict__ wt,
    const float* __restrict__ bias, float* __restrict__ out) {
  __shared__ alignas(128) char Ft[2][16384];  // [64][256B] bf16, swizzled, dbuf

  const int tid = threadIdx.x;
  const int lane = tid & 63, wv = tid >> 6;
  const int lr = lane & 15, lq = lane >> 4;
  const long brow = (long)blockIdx.x * 512;
  const int c0 = wv * 64;

  bf16x8 wf[4][4];
#pragma unroll
  for (int kc = 0; kc < 4; ++kc)
#pragma unroll
    for (int nf = 0; nf < 4; ++nf)
      wf[kc][nf] = *(const bf16x8*)(wt + (long)(c0 + nf * 16 + lr) * 128 + kc * 32 + lq * 8);
  f32x4 bv[4];
#pragma unroll
  for (int nf = 0; nf < 4; ++nf) bv[nf] = *(const f32x4*)(bias + c0 + nf * 16 + lq * 4);

  stage_ftile(f_in, brow, Ft[0], tid);  // stage(0): 4 VMEM

#pragma unroll 1
  for (int t = 0; t < 8; ++t) {
    stage_ftile(f_in, brow + (long)((t < 7) ? t + 1 : 7) * 64, Ft[(t + 1) & 1], tid);
    if (t == 0) { BAR_VM(4); } else { BAR_VM(20); }
    char* F = Ft[t & 1];

    f32x4 acc[4][4];
#pragma unroll
    for (int mf = 0; mf < 4; ++mf)
#pragma unroll
      for (int nf = 0; nf < 4; ++nf) acc[mf][nf] = bv[nf];
#pragma unroll
    for (int kc = 0; kc < 4; ++kc) {
      bf16x8 a[4];
#pragma unroll
      for (int mf = 0; mf < 4; ++mf) {
        int row = mf * 16 + lr, g = kc * 4 + lq;
        int gp = (g & 8) | ((g & 7) ^ (row & 7));
        a[mf] = *(const bf16x8*)(F + row * 256 + gp * 16);
      }
#pragma unroll
      for (int mf = 0; mf < 4; ++mf)
#pragma unroll
        for (int nf = 0; nf < 4; ++nf) acc[mf][nf] = MFMA16(wf[kc][nf], a[mf], acc[mf][nf]);
    }
    BAR_LGKM();  // all Ft[t&1] reads done -> stage(t+2) may overwrite

    long mt0 = brow + (long)t * 64;
#pragma unroll
    for (int mf = 0; mf < 4; ++mf)
#pragma unroll
      for (int nf = 0; nf < 4; ++nf) {
        long row = mt0 + mf * 16 + lr;
        int col = c0 + nf * 16 + lq * 4;
        *(f32x4*)(out + row * 256 + col) = acc[mf][nf];  // stores: S=16
      }
  }
}

extern "C" void kernel_launch(void* const* d_in, const int* in_sizes, int n_in,
                              void* d_out, int out_size, void* d_ws, size_t ws_size,
                              hipStream_t stream) {
  const float* data = (const float*)d_in[0];
  const float* W1_0 = (const float*)d_in[1];
  const float* b1_0 = (const float*)d_in[2];
  const float* W1_1 = (const float*)d_in[3];
  const float* b1_1 = (const float*)d_in[4];
  const float* W2_0 = (const float*)d_in[5];
  const float* b2_0 = (const float*)d_in[6];
  const float* W2_1 = (const float*)d_in[7];
  const float* b2_1 = (const float*)d_in[8];
  const float* W3_0 = (const float*)d_in[9];
  const float* b3_0 = (const float*)d_in[10];
  const float* W3_1 = (const float*)d_in[11];
  const float* b3_1 = (const float*)d_in[12];
  const float* W4_0 = (const float*)d_in[13];
  const float* b4_0 = (const float*)d_in[14];
  const float* W4_1 = (const float*)d_in[15];
  const float* b4_1 = (const float*)d_in[16];
  const float* Wfc = (const float*)d_in[17];
  const float* bfc = (const float*)d_in[18];

  bf16* wsb = (bf16*)d_ws;
  bf16* fA = (bf16*)((char*)d_ws + FA_BYTE);
  bf16* fB = (bf16*)((char*)d_ws + FB_BYTE);
  int* partab = (int*)((char*)d_ws + PT_BYTE);

  prep_pidx_kernel<<<2048, 256, 0, stream>>>(W1_0, W1_1, W2_0, W2_1, W3_0, W3_1, W4_0, W4_1,
                                             Wfc, wsb, data, partab, fA, fB);
  stage1_kernel<<<1024, 256, 0, stream>>>(data, wsb + W10T, b1_0, wsb + W11T, b1_1, fA);
  resblock_kernel<<<512, 256, 0, stream>>>(fA, wsb + W20T, b2_0, wsb + W21T, b2_1, partab, fB);
  resblock_kernel<<<512, 256, 0, stream>>>(fB, wsb + W30T, b3_0, wsb + W31T, b3_1, partab, fA);
  resblock_kernel<<<512, 256, 0, stream>>>(fA, wsb + W40T, b4_0, wsb + W41T, b4_1, partab, fB);
  fc_kernel<<<1024, 256, 0, stream>>>(fB, wsb + WFCT, bfc, (float*)d_out);
}